// Round 1
// baseline (71.767 us; speedup 1.0000x reference)
//
#include <hip/hip_runtime.h>

// y[g,k,n,m] = sum_{i,j} w[i,k,j] * r[m+j],  r[p] = x[g,i,n,(p-2)%7] for
// p in 1..7 else 0;  out[g,k,(n+1)%7,m] = y[g,k,n,m].  (shift==1 folded in)
//
// R7: fuse BOTH groups g=0,1 into one block. w[i,k,j] is g-independent, so
// the previous 448-block grid read every w slab twice (43 MB L2 for a 3 MB
// tensor) and ran 2 unbalanced rounds on 256 CUs (448 = 1.75/CU). New grid
// = 32 kc x 7 n = 224 blocks: exactly one balanced round, w slab loaded
// once per (kc,n) and consumed by 14 accumulators (7 per group). Same-kc
// blocks still share an XCD (bid%8 == kc%8 since 32%8==0) so the slab is
// L2-local. x rows for both groups staged in LDS (2 x 24.8 KB) with the
// width-roll folded in; row addressing swizzled (+4 floats per 32 rows) to
// keep the 4 ic-groups of a wave on disjoint bank quads. i-reduction:
// shfl_xor(16,32) + tiny LDS tree across the 4 waves.

#define NKC 32
#define KC  16

__device__ __forceinline__ int xrow(int i) {   // swizzled LDS row offset
    return i * 12 + ((i >> 5) << 2);
}

__global__ __launch_bounds__(256) void conv_one(
    const float* __restrict__ x,   // (1024, 7, 7) = (g*512+i, n, m)
    const float* __restrict__ w,   // (512, 512, 3) = (i, k, j)
    float* __restrict__ out)       // (1024, 7, 7)
{
    // per group: 512 rows x 12 floats (+ swizzle pad): r[p]=x[g,i,n,(p-2)%7]
    __shared__ __align__(16) float x_s[2][512 * 12 + 64];
    __shared__ float red[4][2][16][7];

    const int b   = blockIdx.x;        // 224
    const int kc  = b & 31;            // same-kc blocks -> same XCD (bid%8)
    const int n   = b >> 5;            // 0..6
    const int tid = threadIdx.x;
    const int kL  = tid & 15;
    const int ic  = tid >> 4;          // 0..15, 32 i each

    // ---- stage x[g, :, n, :] for BOTH groups, width-roll folded in ----
    #pragma unroll
    for (int g = 0; g < 2; ++g) {
        const float* xg = x + (size_t)g * 25088 + n * 7;   // [i*49 + m]
        #pragma unroll
        for (int e = tid; e < 512 * 7; e += 256) {
            const int i  = e / 7;
            const int m  = e % 7;
            const int mm = (m == 6) ? 1 : (m + 2);          // (m+2) mod 7 -> 1..7
            x_s[g][xrow(i) + mm] = xg[i * 49 + m];
        }
        #pragma unroll
        for (int i = tid; i < 512; i += 256) {              // zero pads p=0,8
            x_s[g][xrow(i) + 0] = 0.f;
            x_s[g][xrow(i) + 8] = 0.f;
        }
    }
    __syncthreads();

    // ---- accumulate over this thread's 32 i values, both groups ----
    const int k = kc * KC + kL;
    const float* wp  = w + (size_t)(ic * 32) * 1536 + k * 3;
    const float* xr0 = &x_s[0][xrow(ic * 32)];              // advance 12/iter
    const float* xr1 = &x_s[1][xrow(ic * 32)];

    float a0 = 0.f, a1 = 0.f, a2 = 0.f, a3 = 0.f, a4 = 0.f, a5 = 0.f, a6 = 0.f;
    float b0 = 0.f, b1 = 0.f, b2 = 0.f, b3 = 0.f, b4 = 0.f, b5 = 0.f, b6 = 0.f;

    #pragma unroll 4
    for (int ii = 0; ii < 32; ++ii) {
        const float w0 = wp[0], w1 = wp[1], w2 = wp[2];
        wp += 1536;
        const float4 ra = *(const float4*)(xr0);            // g0 r[0..3]
        const float4 rb = *(const float4*)(xr0 + 4);        // g0 r[4..7]
        const float  r8 = xr0[8];
        xr0 += 12;
        const float4 sa = *(const float4*)(xr1);            // g1 r[0..3]
        const float4 sb = *(const float4*)(xr1 + 4);        // g1 r[4..7]
        const float  s8 = xr1[8];
        xr1 += 12;

        a0 += w0 * ra.x + w1 * ra.y + w2 * ra.z;
        a1 += w0 * ra.y + w1 * ra.z + w2 * ra.w;
        a2 += w0 * ra.z + w1 * ra.w + w2 * rb.x;
        a3 += w0 * ra.w + w1 * rb.x + w2 * rb.y;
        a4 += w0 * rb.x + w1 * rb.y + w2 * rb.z;
        a5 += w0 * rb.y + w1 * rb.z + w2 * rb.w;
        a6 += w0 * rb.z + w1 * rb.w + w2 * r8;

        b0 += w0 * sa.x + w1 * sa.y + w2 * sa.z;
        b1 += w0 * sa.y + w1 * sa.z + w2 * sa.w;
        b2 += w0 * sa.z + w1 * sa.w + w2 * sb.x;
        b3 += w0 * sa.w + w1 * sb.x + w2 * sb.y;
        b4 += w0 * sb.x + w1 * sb.y + w2 * sb.z;
        b5 += w0 * sb.y + w1 * sb.z + w2 * sb.w;
        b6 += w0 * sb.z + w1 * sb.w + w2 * s8;
    }

    // ---- reduce the 4 ic-groups within each wave (lane bits 4,5) ----
    a0 += __shfl_xor(a0, 16); a0 += __shfl_xor(a0, 32);
    a1 += __shfl_xor(a1, 16); a1 += __shfl_xor(a1, 32);
    a2 += __shfl_xor(a2, 16); a2 += __shfl_xor(a2, 32);
    a3 += __shfl_xor(a3, 16); a3 += __shfl_xor(a3, 32);
    a4 += __shfl_xor(a4, 16); a4 += __shfl_xor(a4, 32);
    a5 += __shfl_xor(a5, 16); a5 += __shfl_xor(a5, 32);
    a6 += __shfl_xor(a6, 16); a6 += __shfl_xor(a6, 32);

    b0 += __shfl_xor(b0, 16); b0 += __shfl_xor(b0, 32);
    b1 += __shfl_xor(b1, 16); b1 += __shfl_xor(b1, 32);
    b2 += __shfl_xor(b2, 16); b2 += __shfl_xor(b2, 32);
    b3 += __shfl_xor(b3, 16); b3 += __shfl_xor(b3, 32);
    b4 += __shfl_xor(b4, 16); b4 += __shfl_xor(b4, 32);
    b5 += __shfl_xor(b5, 16); b5 += __shfl_xor(b5, 32);
    b6 += __shfl_xor(b6, 16); b6 += __shfl_xor(b6, 32);

    const int wave = tid >> 6;
    if ((tid & 63) < 16) {
        red[wave][0][kL][0] = a0; red[wave][0][kL][1] = a1;
        red[wave][0][kL][2] = a2; red[wave][0][kL][3] = a3;
        red[wave][0][kL][4] = a4; red[wave][0][kL][5] = a5;
        red[wave][0][kL][6] = a6;
        red[wave][1][kL][0] = b0; red[wave][1][kL][1] = b1;
        red[wave][1][kL][2] = b2; red[wave][1][kL][3] = b3;
        red[wave][1][kL][4] = b4; red[wave][1][kL][5] = b5;
        red[wave][1][kL][6] = b6;
    }
    __syncthreads();

    // ---- final sum across the 4 waves + store (both groups) ----
    if (tid < 224) {
        const int gg = tid / 112;          // group
        const int r  = tid - gg * 112;
        const int kk = r & 15;             // k within chunk
        const int m  = r >> 4;             // 0..6
        const float s = red[0][gg][kk][m] + red[1][gg][kk][m]
                      + red[2][gg][kk][m] + red[3][gg][kk][m];
        const int nOut = (n + 1) % 7;      // final height roll
        out[((size_t)(gg * 512 + kc * KC + kk) * 7 + nOut) * 7 + m] = s;
    }
}

extern "C" void kernel_launch(void* const* d_in, const int* in_sizes, int n_in,
                              void* d_out, int out_size, void* d_ws, size_t ws_size,
                              hipStream_t stream) {
    const float* x = (const float*)d_in[0];
    const float* w = (const float*)d_in[1];
    float* out = (float*)d_out;
    conv_one<<<dim3(NKC * 7), dim3(256), 0, stream>>>(x, w, out);
}

// Round 2
// 64.561 us; speedup vs baseline: 1.1116x; 1.1116x over previous
//
#include <hip/hip_runtime.h>

// y[g,k,n,m] = sum_{i,j} w[i,k,j] * r[m+j],  r[p] = x[g,i,n,(p-2)%7] for
// p in 1..7 else 0;  out[g,k,(n+1)%7,m] = y[g,k,n,m].  (shift==1 folded in)
//
// R8: R7's g-fusion (w read once per (kc,n), one balanced 224-block round)
// was right, but 256 threads @ 1 block/CU = 1 wave/SIMD -> zero latency
// hiding and a 32-iter serial loop; it regressed vs R6 (71.8 vs 67.1).
// Fix: 512 threads/block = 32 ic-groups x 16 kL, 16 i per thread.
//   - 8 waves/CU (2/SIMD): w-load + ds_read latency now overlapped
//   - inner loop halved to 16 iterations
//   - grid stays 32 kc x 7 n = 224, one balanced round, bid%8==kc%8 keeps
//     each w slab on one XCD's L2
// Swizzle upgraded to +4 floats per 16 rows: a wave's 4 concurrent
// ic-groups are 16 rows (192 floats) apart -> same bank without swizzle;
// (i>>4)<<2 gives bank offsets 0,4,8,12 (conflict-free), still 16B-aligned.
// Reduction: shfl_xor(16,32) folds the 4 ic-groups within each wave, then
// an 8-wave LDS tree.

#define NKC 32
#define KC  16

__device__ __forceinline__ int xrow(int i) {   // swizzled LDS row offset
    return i * 12 + ((i >> 4) << 2);
}

__global__ __launch_bounds__(512) void conv_one(
    const float* __restrict__ x,   // (1024, 7, 7) = (g*512+i, n, m)
    const float* __restrict__ w,   // (512, 512, 3) = (i, k, j)
    float* __restrict__ out)       // (1024, 7, 7)
{
    // per group: 512 rows x 12 floats (+ swizzle pad): r[p]=x[g,i,n,(p-2)%7]
    __shared__ __align__(16) float x_s[2][512 * 12 + 128];
    __shared__ float red[8][2][16][7];

    const int b   = blockIdx.x;        // 224
    const int kc  = b & 31;            // same-kc blocks -> same XCD (bid%8)
    const int n   = b >> 5;            // 0..6
    const int tid = threadIdx.x;
    const int kL  = tid & 15;
    const int ic  = tid >> 4;          // 0..31, 16 i each

    // ---- stage x[g, :, n, :] for BOTH groups, width-roll folded in ----
    #pragma unroll
    for (int g = 0; g < 2; ++g) {
        const float* xg = x + (size_t)g * 25088 + n * 7;   // [i*49 + m]
        #pragma unroll
        for (int e = tid; e < 512 * 7; e += 512) {
            const int i  = e / 7;
            const int m  = e % 7;
            const int mm = (m == 6) ? 1 : (m + 2);          // (m+2) mod 7 -> 1..7
            x_s[g][xrow(i) + mm] = xg[i * 49 + m];
        }
        if (tid < 512) {                                    // zero pads p=0,8
            x_s[g][xrow(tid) + 0] = 0.f;
            x_s[g][xrow(tid) + 8] = 0.f;
        }
    }
    __syncthreads();

    // ---- accumulate over this thread's 16 i values, both groups ----
    const int k = kc * KC + kL;
    const float* wp  = w + (size_t)(ic * 16) * 1536 + k * 3;
    const float* xr0 = &x_s[0][xrow(ic * 16)];              // advance 12/iter
    const float* xr1 = &x_s[1][xrow(ic * 16)];

    float a0 = 0.f, a1 = 0.f, a2 = 0.f, a3 = 0.f, a4 = 0.f, a5 = 0.f, a6 = 0.f;
    float b0 = 0.f, b1 = 0.f, b2 = 0.f, b3 = 0.f, b4 = 0.f, b5 = 0.f, b6 = 0.f;

    #pragma unroll 4
    for (int ii = 0; ii < 16; ++ii) {
        const float w0 = wp[0], w1 = wp[1], w2 = wp[2];
        wp += 1536;
        const float4 ra = *(const float4*)(xr0);            // g0 r[0..3]
        const float4 rb = *(const float4*)(xr0 + 4);        // g0 r[4..7]
        const float  r8 = xr0[8];
        xr0 += 12;
        const float4 sa = *(const float4*)(xr1);            // g1 r[0..3]
        const float4 sb = *(const float4*)(xr1 + 4);        // g1 r[4..7]
        const float  s8 = xr1[8];
        xr1 += 12;

        a0 += w0 * ra.x + w1 * ra.y + w2 * ra.z;
        a1 += w0 * ra.y + w1 * ra.z + w2 * ra.w;
        a2 += w0 * ra.z + w1 * ra.w + w2 * rb.x;
        a3 += w0 * ra.w + w1 * rb.x + w2 * rb.y;
        a4 += w0 * rb.x + w1 * rb.y + w2 * rb.z;
        a5 += w0 * rb.y + w1 * rb.z + w2 * rb.w;
        a6 += w0 * rb.z + w1 * rb.w + w2 * r8;

        b0 += w0 * sa.x + w1 * sa.y + w2 * sa.z;
        b1 += w0 * sa.y + w1 * sa.z + w2 * sa.w;
        b2 += w0 * sa.z + w1 * sa.w + w2 * sb.x;
        b3 += w0 * sa.w + w1 * sb.x + w2 * sb.y;
        b4 += w0 * sb.x + w1 * sb.y + w2 * sb.z;
        b5 += w0 * sb.y + w1 * sb.z + w2 * sb.w;
        b6 += w0 * sb.z + w1 * sb.w + w2 * s8;
    }

    // ---- reduce the 4 ic-groups within each wave (lane bits 4,5) ----
    a0 += __shfl_xor(a0, 16); a0 += __shfl_xor(a0, 32);
    a1 += __shfl_xor(a1, 16); a1 += __shfl_xor(a1, 32);
    a2 += __shfl_xor(a2, 16); a2 += __shfl_xor(a2, 32);
    a3 += __shfl_xor(a3, 16); a3 += __shfl_xor(a3, 32);
    a4 += __shfl_xor(a4, 16); a4 += __shfl_xor(a4, 32);
    a5 += __shfl_xor(a5, 16); a5 += __shfl_xor(a5, 32);
    a6 += __shfl_xor(a6, 16); a6 += __shfl_xor(a6, 32);

    b0 += __shfl_xor(b0, 16); b0 += __shfl_xor(b0, 32);
    b1 += __shfl_xor(b1, 16); b1 += __shfl_xor(b1, 32);
    b2 += __shfl_xor(b2, 16); b2 += __shfl_xor(b2, 32);
    b3 += __shfl_xor(b3, 16); b3 += __shfl_xor(b3, 32);
    b4 += __shfl_xor(b4, 16); b4 += __shfl_xor(b4, 32);
    b5 += __shfl_xor(b5, 16); b5 += __shfl_xor(b5, 32);
    b6 += __shfl_xor(b6, 16); b6 += __shfl_xor(b6, 32);

    const int wave = tid >> 6;          // 0..7
    if ((tid & 63) < 16) {
        red[wave][0][kL][0] = a0; red[wave][0][kL][1] = a1;
        red[wave][0][kL][2] = a2; red[wave][0][kL][3] = a3;
        red[wave][0][kL][4] = a4; red[wave][0][kL][5] = a5;
        red[wave][0][kL][6] = a6;
        red[wave][1][kL][0] = b0; red[wave][1][kL][1] = b1;
        red[wave][1][kL][2] = b2; red[wave][1][kL][3] = b3;
        red[wave][1][kL][4] = b4; red[wave][1][kL][5] = b5;
        red[wave][1][kL][6] = b6;
    }
    __syncthreads();

    // ---- final sum across the 8 waves + store (both groups) ----
    if (tid < 224) {
        const int gg = tid / 112;          // group
        const int r  = tid - gg * 112;
        const int kk = r & 15;             // k within chunk
        const int m  = r >> 4;             // 0..6
        float s = 0.f;
        #pragma unroll
        for (int wv = 0; wv < 8; ++wv) s += red[wv][gg][kk][m];
        const int nOut = (n + 1) % 7;      // final height roll
        out[((size_t)(gg * 512 + kc * KC + kk) * 7 + nOut) * 7 + m] = s;
    }
}

extern "C" void kernel_launch(void* const* d_in, const int* in_sizes, int n_in,
                              void* d_out, int out_size, void* d_ws, size_t ws_size,
                              hipStream_t stream) {
    const float* x = (const float*)d_in[0];
    const float* w = (const float*)d_in[1];
    float* out = (float*)d_out;
    conv_one<<<dim3(NKC * 7), dim3(512), 0, stream>>>(x, w, out);
}